// Round 3
// baseline (158.654 us; speedup 1.0000x reference)
//
#include <hip/hip_runtime.h>

#define EPS 1e-6f

typedef float v4f __attribute__((ext_vector_type(4)));

__device__ __forceinline__ float dot4(v4f a) {
    return a.x * a.x + a.y * a.y + a.z * a.z + a.w * a.w;
}

__device__ __forceinline__ float wave_reduce(float s) {
#pragma unroll
    for (int off = 32; off; off >>= 1) s += __shfl_xor(s, off);
    return s;
}

// One block = one q row (6144) + one k row (1024). 256 threads:
// 6 float4/thread of q + 1 float4/thread of k, loaded once into registers
// (nontemporal — zero reuse, keep L2/L3 for the weight vectors), both
// block-wide sumsq reductions share a single __syncthreads, then scale and
// nontemporal-store. Uniform grid, no k-only tail phase.
template <int B, int D1, int D2>
__global__ __launch_bounds__(256) void qk_rmsnorm(const float* __restrict__ q,
                                                  const float* __restrict__ k,
                                                  const float* __restrict__ qw,
                                                  const float* __restrict__ kw,
                                                  float* __restrict__ oq,
                                                  float* __restrict__ ok) {
    constexpr int VQ = D1 / (4 * 256);  // 6
    static_assert(D2 == 4 * 256, "k row must be exactly one float4 per thread");

    const int b = blockIdx.x;
    const int t = threadIdx.x;

    const v4f* __restrict__ qr = reinterpret_cast<const v4f*>(q + (size_t)b * D1);
    const v4f* __restrict__ kr = reinterpret_cast<const v4f*>(k + (size_t)b * D2);
    v4f* __restrict__ oqr = reinterpret_cast<v4f*>(oq + (size_t)b * D1);
    v4f* __restrict__ okr = reinterpret_cast<v4f*>(ok + (size_t)b * D2);
    const v4f* __restrict__ qwv = reinterpret_cast<const v4f*>(qw);
    const v4f* __restrict__ kwv = reinterpret_cast<const v4f*>(kw);

    // Loads: issue all 7 before any use so they coalesce into one burst.
    v4f vq[VQ];
#pragma unroll
    for (int j = 0; j < VQ; ++j) vq[j] = __builtin_nontemporal_load(&qr[t + j * 256]);
    const v4f vk = __builtin_nontemporal_load(&kr[t]);

    float sq = 0.f;
#pragma unroll
    for (int j = 0; j < VQ; ++j) sq += dot4(vq[j]);
    float sk = dot4(vk);

    sq = wave_reduce(sq);
    sk = wave_reduce(sk);

    __shared__ float redq[4], redk[4];
    const int wid = t >> 6;
    if ((t & 63) == 0) {
        redq[wid] = sq;
        redk[wid] = sk;
    }
    __syncthreads();
    sq = redq[0] + redq[1] + redq[2] + redq[3];
    sk = redk[0] + redk[1] + redk[2] + redk[3];

    const float invq = rsqrtf(sq * (1.0f / (float)D1) + EPS);
    const float invk = rsqrtf(sk * (1.0f / (float)D2) + EPS);

#pragma unroll
    for (int j = 0; j < VQ; ++j) {
        const v4f wj = qwv[t + j * 256];
        __builtin_nontemporal_store(vq[j] * invq * wj, &oqr[t + j * 256]);
    }
    const v4f wk = kwv[t];
    __builtin_nontemporal_store(vk * invk * wk, &okr[t]);
}

extern "C" void kernel_launch(void* const* d_in, const int* in_sizes, int n_in,
                              void* d_out, int out_size, void* d_ws, size_t ws_size,
                              hipStream_t stream) {
    (void)in_sizes; (void)n_in; (void)d_ws; (void)ws_size; (void)out_size;

    constexpr int B = 16384;
    constexpr int D1 = 6144;
    constexpr int D2 = 1024;

    const float* q = (const float*)d_in[0];
    const float* k = (const float*)d_in[1];
    const float* qw = (const float*)d_in[2];
    const float* kw = (const float*)d_in[3];

    float* out_q = (float*)d_out;
    float* out_k = out_q + (size_t)B * D1;

    qk_rmsnorm<B, D1, D2><<<B, 256, 0, stream>>>(q, k, qw, kw, out_q, out_k);
}